// Round 10
// baseline (985.807 us; speedup 1.0000x reference)
//
#include <hip/hip_runtime.h>

#define D 64
#define LAYERS 3

typedef float  f4  __attribute__((ext_vector_type(4)));
typedef short  s8v __attribute__((ext_vector_type(8)));
typedef short  s4v __attribute__((ext_vector_type(4)));
typedef unsigned short ushort_t;

__device__ __forceinline__ unsigned short f2bf(float x) {
    unsigned int u = __float_as_uint(x);
    unsigned int r = (u + 0x7fffu + ((u >> 16) & 1u)) >> 16;
    return (unsigned short)r;
}
__device__ __forceinline__ float bf2f(unsigned short h) {
    return __uint_as_float(((unsigned int)h) << 16);
}

// ---------------- CSR build ----------------

__global__ void k_count(const int* __restrict__ dst, int* __restrict__ cnt, int E) {
    int e = blockIdx.x * blockDim.x + threadIdx.x;
    if (e < E) atomicAdd(&cnt[dst[e]], 1);
}

__global__ __launch_bounds__(1024) void k_scan(const int* __restrict__ cnt,
                                               int* __restrict__ row_start,
                                               float* __restrict__ inv_deg, int N) {
    __shared__ int buf[1024];
    int tid = threadIdx.x;
    int per = (N + 1023) >> 10;
    int begin = tid * per;
    int end = min(begin + per, N);
    int s = 0;
    for (int i = begin; i < end; i++) s += cnt[i];
    buf[tid] = s;
    __syncthreads();
    for (int off = 1; off < 1024; off <<= 1) {
        int v = 0;
        if (tid >= off) v = buf[tid - off];
        __syncthreads();
        buf[tid] += v;
        __syncthreads();
    }
    int run = buf[tid] - s;
    for (int i = begin; i < end; i++) {
        row_start[i] = run;
        int c = cnt[i];
        inv_deg[i] = 1.0f / (float)(c > 1 ? c : 1);
        run += c;
    }
    if (begin < N && end == N) row_start[N] = run;
}

__global__ void k_fill(const int* __restrict__ src, const int* __restrict__ dst,
                       const int* __restrict__ row_start, int* __restrict__ cursor,
                       int* __restrict__ eids, int* __restrict__ srcs,
                       int* __restrict__ pdst, int* __restrict__ pos, int E) {
    int e = blockIdx.x * blockDim.x + threadIdx.x;
    if (e >= E) return;
    int d = dst[e];
    int p = row_start[d] + atomicAdd(&cursor[d], 1);
    eids[p] = e;
    srcs[p] = src[e];
    pdst[p] = d;
    pos[e] = p;
}

// ---------------- fused: permute ea0 -> pea (bf16, p-order) AND x0 -> xb (bf16) ----------------
__global__ __launch_bounds__(256) void k_permcvt(const float* __restrict__ ea,
                                                 const int* __restrict__ pos,
                                                 ushort_t* __restrict__ pea, int E,
                                                 const float* __restrict__ x,
                                                 ushort_t* __restrict__ xb, int xtotal8,
                                                 int pblocks) {
    if ((int)blockIdx.x < pblocks) {
        int t = blockIdx.x * blockDim.x + threadIdx.x;
        int e = t >> 3;
        if (e >= E) return;
        int seg = t & 7;
        const float* rp = ea + (size_t)e * D + seg * 8;
        f4 a0 = *(const f4*)rp;
        f4 a1 = *(const f4*)(rp + 4);
        s8v o;
        #pragma unroll
        for (int i = 0; i < 4; i++) {
            o[i]     = (short)f2bf(a0[i]);
            o[4 + i] = (short)f2bf(a1[i]);
        }
        int p = pos[e];
        *(s8v*)(pea + (size_t)p * D + seg * 8) = o;
    } else {
        int t = (blockIdx.x - pblocks) * blockDim.x + threadIdx.x;
        if (t >= xtotal8) return;
        const float* rp = x + (size_t)t * 8;
        f4 a0 = *(const f4*)rp;
        f4 a1 = *(const f4*)(rp + 4);
        s8v o;
        #pragma unroll
        for (int i = 0; i < 4; i++) {
            o[i]     = (short)f2bf(a0[i]);
            o[4 + i] = (short)f2bf(a1[i]);
        }
        *(s8v*)(xb + (size_t)t * 8) = o;
    }
}

// ---------------- prepack edge-MLP weight fragments (per-lane layout) ----------------
__global__ __launch_bounds__(64) void k_prepw(const float* __restrict__ EWe,
                                              const float* __restrict__ EW1,
                                              s8v* __restrict__ wbuf) {
    int L = blockIdx.x;
    const float* We = EWe + (size_t)L * D * D;
    const float* W1 = EW1 + (size_t)L * D * D;
    s8v* wb = wbuf + (size_t)L * 1536;
    int lane = threadIdx.x;
    int c = lane & 15, g = lane >> 4;
    #pragma unroll
    for (int nt = 0; nt < 4; nt++) {
        #pragma unroll
        for (int kt = 0; kt < 2; kt++) {
            s8v h, l, w1;
            #pragma unroll
            for (int i = 0; i < 8; i++) {
                int k1 = 32 * kt + 8 * g + i;                       // natural k (GEMM1)
                float w = We[k1 * D + 16 * nt + c];
                unsigned short hb = f2bf(w);
                h[i] = (short)hb;
                l[i] = (short)f2bf(w - bf2f(hb));
                int k2 = 32 * kt + 16 * (i >> 2) + 4 * g + (i & 3); // pi-order (GEMM2)
                w1[i] = (short)f2bf(W1[k2 * D + 16 * nt + c]);
            }
            int f = nt * 2 + kt;
            wb[(0 * 8 + f) * 64 + lane] = h;
            wb[(1 * 8 + f) * 64 + lane] = l;
            wb[(2 * 8 + f) * 64 + lane] = w1;
        }
    }
}

// ---------------- aggregation: xb gathered (bf16), pea streamed (bf16) ----------------
__global__ __launch_bounds__(256) void k_agg_seq(const ushort_t* __restrict__ xb,
                                                 const ushort_t* __restrict__ pea,
                                                 const int* __restrict__ row_start,
                                                 const int* __restrict__ srcs,
                                                 float* __restrict__ Sx, float* __restrict__ Se,
                                                 int N) {
    int n = blockIdx.x * 4 + threadIdx.y;
    if (n >= N) return;
    int j = threadIdx.x;
    int p0 = row_start[n], p1 = row_start[n + 1];
    float ax0 = 0.f, ax1 = 0.f, ax2 = 0.f, ax3 = 0.f;
    float ae0 = 0.f, ae1 = 0.f, ae2 = 0.f, ae3 = 0.f;
    int p = p0;
    for (; p + 4 <= p1; p += 4) {
        int s0 = srcs[p], s1 = srcs[p + 1], s2 = srcs[p + 2], s3 = srcs[p + 3];
        ax0 += bf2f(xb[(size_t)s0 * D + j]);
        ax1 += bf2f(xb[(size_t)s1 * D + j]);
        ax2 += bf2f(xb[(size_t)s2 * D + j]);
        ax3 += bf2f(xb[(size_t)s3 * D + j]);
        ae0 += bf2f(pea[(size_t)p * D + j]);
        ae1 += bf2f(pea[(size_t)(p + 1) * D + j]);
        ae2 += bf2f(pea[(size_t)(p + 2) * D + j]);
        ae3 += bf2f(pea[(size_t)(p + 3) * D + j]);
    }
    for (; p < p1; p++) {
        ax0 += bf2f(xb[(size_t)srcs[p] * D + j]);
        ae0 += bf2f(pea[(size_t)p * D + j]);
    }
    Sx[(size_t)n * D + j] = (ax0 + ax1) + (ax2 + ax3);
    Se[(size_t)n * D + j] = (ae0 + ae1) + (ae2 + ae3);
}

// ---------------- node update (emits f32 + bf16 copies) ----------------
__global__ __launch_bounds__(256) void k_node(const float* __restrict__ x,
                                              const float* __restrict__ Sx,
                                              const float* __restrict__ Se,
                                              const float* __restrict__ inv_deg,
                                              const float* __restrict__ Wr,
                                              const float* __restrict__ Wn,
                                              const float* __restrict__ We,
                                              const float* __restrict__ bias,
                                              float* __restrict__ xo,
                                              ushort_t* __restrict__ xob,
                                              int N, int do_relu) {
    __shared__ float sWr[D * D], sWn[D * D], sWe[D * D];
    __shared__ float rx[4][D], rsx[4][D], rse[4][D];
    int tid = threadIdx.y * 64 + threadIdx.x;
    for (int i = tid; i < D * D; i += 256) {
        sWr[i] = Wr[i];
        sWn[i] = Wn[i];
        sWe[i] = We[i];
    }
    int j = threadIdx.x;
    int ty = threadIdx.y;
    float bj = bias[j];
    for (int g = blockIdx.x; g * 4 < N; g += gridDim.x) {
        int n = g * 4 + ty;
        __syncthreads();
        if (n < N) {
            rx[ty][j]  = x[(size_t)n * D + j];
            rsx[ty][j] = Sx[(size_t)n * D + j];
            rse[ty][j] = Se[(size_t)n * D + j];
        }
        __syncthreads();
        if (n < N) {
            float a0 = 0.f, a1 = 0.f, a2 = 0.f;
            #pragma unroll 8
            for (int k = 0; k < D; k++) {
                a0 += rx[ty][k]  * sWr[k * D + j];
                a1 += rsx[ty][k] * sWn[k * D + j];
                a2 += rse[ty][k] * sWe[k * D + j];
            }
            float v = a0 + inv_deg[n] * (a1 + a2) + bj;
            if (do_relu) v = fmaxf(v, 0.f);
            xo[(size_t)n * D + j] = v;
            if (xob) xob[(size_t)n * D + j] = f2bf(v);
        }
    }
}

// ---------------- s/t features -> bf16 (be folded into sf bias) ----------------
__global__ __launch_bounds__(256) void k_st(const float* __restrict__ x,
                                            const float* __restrict__ Ws, const float* __restrict__ bs,
                                            const float* __restrict__ Wt, const float* __restrict__ bt,
                                            const float* __restrict__ be,
                                            ushort_t* __restrict__ sfb, ushort_t* __restrict__ tfb,
                                            int N) {
    __shared__ float sWs[D * D], sWt[D * D];
    __shared__ float rx[4][D];
    int tid = threadIdx.y * 64 + threadIdx.x;
    for (int i = tid; i < D * D; i += 256) {
        sWs[i] = Ws[i];
        sWt[i] = Wt[i];
    }
    int j = threadIdx.x;
    int ty = threadIdx.y;
    float bsj = bs[j] + be[j];
    float btj = bt[j];
    for (int g = blockIdx.x; g * 4 < N; g += gridDim.x) {
        int n = g * 4 + ty;
        __syncthreads();
        if (n < N) rx[ty][j] = x[(size_t)n * D + j];
        __syncthreads();
        if (n < N) {
            float a0 = 0.f, a1 = 0.f;
            #pragma unroll 8
            for (int k = 0; k < D; k++) {
                float xv = rx[ty][k];
                a0 += xv * sWs[k * D + j];
                a1 += xv * sWt[k * D + j];
            }
            sfb[(size_t)n * D + j] = f2bf(a0 + bsj);
            tfb[(size_t)n * D + j] = f2bf(a1 + btj);
        }
    }
}

// ---------------- edge MLP via MFMA (prepacked weight frags, 4 waves/EU) ----------------
// h^T = We^T @ ea^T ; out^T = W1^T @ h^T (lane's D-col = edge).
// sf/tf bf16 gathers (L3-resident); be folded into sf. ea_in/out_p may alias.
template<int MODE>
__global__ __launch_bounds__(256, 4) void k_edge_mfma(
        const ushort_t* ea_in,
        const int* __restrict__ srcA, const int* __restrict__ dstA,
        const int* __restrict__ emap,
        const ushort_t* __restrict__ sfb, const ushort_t* __restrict__ tfb,
        const s8v* __restrict__ wb,
        const float* __restrict__ b1,
        ushort_t* out_p, float* __restrict__ out_e, int E) {
    int lane = threadIdx.x & 63;
    int wid  = threadIdx.x >> 6;
    int c = lane & 15;
    int g = lane >> 4;

    s8v weh[4][2], wel[4][2], w1f[4][2];
    #pragma unroll
    for (int nt = 0; nt < 4; nt++) {
        #pragma unroll
        for (int kt = 0; kt < 2; kt++) {
            int f = nt * 2 + kt;
            weh[nt][kt] = wb[(0 * 8 + f) * 64 + lane];
            wel[nt][kt] = wb[(1 * 8 + f) * 64 + lane];
            w1f[nt][kt] = wb[(2 * 8 + f) * 64 + lane];
        }
    }
    f4 b1v[4];
    #pragma unroll
    for (int nt = 0; nt < 4; nt++) {
        b1v[nt] = *(const f4*)&b1[16 * nt + 4 * g];
    }

    int tiles = (E + 15) >> 4;
    for (int t = blockIdx.x * 4 + wid; t < tiles; t += gridDim.x * 4) {
        int idx = t * 16 + c;
        int ic = idx < E ? idx : E - 1;
        const ushort_t* ear = ea_in + (size_t)ic * D;

        s8v eaf[2];
        #pragma unroll
        for (int kt = 0; kt < 2; kt++) {
            eaf[kt] = *(const s8v*)(ear + 32 * kt + 8 * g);
        }

        // GEMM1: h^T = We^T ea^T (hi + lo)
        f4 acc[4];
        #pragma unroll
        for (int nt = 0; nt < 4; nt++) acc[nt] = (f4){0.f, 0.f, 0.f, 0.f};
        #pragma unroll
        for (int nt = 0; nt < 4; nt++) {
            #pragma unroll
            for (int kt = 0; kt < 2; kt++) {
                acc[nt] = __builtin_amdgcn_mfma_f32_16x16x32_bf16(weh[nt][kt], eaf[kt], acc[nt], 0, 0, 0);
                acc[nt] = __builtin_amdgcn_mfma_f32_16x16x32_bf16(wel[nt][kt], eaf[kt], acc[nt], 0, 0, 0);
            }
        }

        // epilogue 1: + sf[src](+be) + tf[dst], relu, pack GEMM2 B-frags
        int s = srcA[ic], d = dstA[ic];
        const ushort_t* sr = sfb + (size_t)s * D;
        const ushort_t* tr = tfb + (size_t)d * D;
        s8v hf[2];
        #pragma unroll
        for (int nt = 0; nt < 4; nt++) {
            s4v sgv = *(const s4v*)(sr + 16 * nt + 4 * g);
            s4v tgv = *(const s4v*)(tr + 16 * nt + 4 * g);
            #pragma unroll
            for (int r = 0; r < 4; r++) {
                float hv = acc[nt][r] + bf2f((ushort_t)sgv[r]) + bf2f((ushort_t)tgv[r]);
                hv = fmaxf(hv, 0.f);
                hf[nt >> 1][((nt & 1) << 2) + r] = (short)f2bf(hv);
            }
        }

        // GEMM2: out^T = W1^T h^T
        f4 out[4];
        #pragma unroll
        for (int nt = 0; nt < 4; nt++) out[nt] = (f4){0.f, 0.f, 0.f, 0.f};
        #pragma unroll
        for (int nt = 0; nt < 4; nt++) {
            #pragma unroll
            for (int kt = 0; kt < 2; kt++) {
                out[nt] = __builtin_amdgcn_mfma_f32_16x16x32_bf16(w1f[nt][kt], hf[kt], out[nt], 0, 0, 0);
            }
        }

        if (idx < E) {
            #pragma unroll
            for (int nt = 0; nt < 4; nt++) out[nt] += b1v[nt];
            ushort_t* prow = out_p + (size_t)idx * D;
            #pragma unroll
            for (int nt = 0; nt < 4; nt++) {
                s4v ov;
                #pragma unroll
                for (int r = 0; r < 4; r++) ov[r] = (short)f2bf(out[nt][r]);
                *(s4v*)(prow + 16 * nt + 4 * g) = ov;
            }
            if (MODE == 1) {
                float* orow = out_e + (size_t)emap[ic] * D;
                #pragma unroll
                for (int nt = 0; nt < 4; nt++) *(f4*)&orow[16 * nt + 4 * g] = out[nt];
            }
        }
    }
}

extern "C" void kernel_launch(void* const* d_in, const int* in_sizes, int n_in,
                              void* d_out, int out_size, void* d_ws, size_t ws_size,
                              hipStream_t stream) {
    const float* x0  = (const float*)d_in[0];
    const int*   ei  = (const int*)d_in[1];
    const float* ea0 = (const float*)d_in[2];
    const float* Wr  = (const float*)d_in[3];
    const float* Wn  = (const float*)d_in[4];
    const float* We  = (const float*)d_in[5];
    const float* b   = (const float*)d_in[6];
    const float* EWe = (const float*)d_in[7];
    const float* Ebe = (const float*)d_in[8];
    const float* EWs = (const float*)d_in[9];
    const float* Ebs = (const float*)d_in[10];
    const float* EWt = (const float*)d_in[11];
    const float* Ebt = (const float*)d_in[12];
    const float* EW1 = (const float*)d_in[13];
    const float* Eb1 = (const float*)d_in[14];

    const int N = in_sizes[0] / D;
    const int E = in_sizes[1] / 2;
    const int* src = ei;
    const int* dst = ei + E;

    char* ws = (char*)d_ws;
    size_t off = 0;
    auto alloc = [&](size_t bytes) {
        void* p = ws + off;
        off += (bytes + 255) & ~(size_t)255;
        return p;
    };
    int*      cntcur    = (int*)alloc((size_t)2 * N * 4);
    int*      cnt       = cntcur;
    int*      cursor    = cntcur + N;
    int*      row_start = (int*)alloc((size_t)(N + 1) * 4);
    int*      eids      = (int*)alloc((size_t)E * 4);
    int*      srcs      = (int*)alloc((size_t)E * 4);
    int*      pdst      = (int*)alloc((size_t)E * 4);
    int*      pos       = (int*)alloc((size_t)E * 4);
    float*    inv_deg   = (float*)alloc((size_t)N * 4);
    float*    Sx        = (float*)alloc((size_t)N * D * 4);
    float*    Se        = (float*)alloc((size_t)N * D * 4);
    float*    x1        = (float*)alloc((size_t)N * D * 4);
    float*    x2        = (float*)alloc((size_t)N * D * 4);
    ushort_t* xb0       = (ushort_t*)alloc((size_t)N * D * 2);
    ushort_t* xb1       = (ushort_t*)alloc((size_t)N * D * 2);
    ushort_t* sfb       = (ushort_t*)alloc((size_t)N * D * 2);
    ushort_t* tfb       = (ushort_t*)alloc((size_t)N * D * 2);
    s8v*      wbuf      = (s8v*)alloc((size_t)2 * 1536 * 16);
    ushort_t* pea       = (ushort_t*)alloc((size_t)E * D * 2);

    float* outx  = (float*)d_out;
    float* outea = (float*)d_out + (size_t)N * D;

    hipMemsetAsync(cntcur, 0, (size_t)2 * N * 4, stream);
    k_count<<<(E + 255) / 256, 256, 0, stream>>>(dst, cnt, E);
    k_scan<<<1, 1024, 0, stream>>>(cnt, row_start, inv_deg, N);
    k_fill<<<(E + 255) / 256, 256, 0, stream>>>(src, dst, row_start, cursor, eids, srcs, pdst, pos, E);
    {
        int pblocks = (E * 8 + 255) / 256;
        int xblocks = (N * D / 8 + 255) / 256;
        k_permcvt<<<pblocks + xblocks, 256, 0, stream>>>(ea0, pos, pea, E, x0, xb0, N * D / 8, pblocks);
    }
    k_prepw<<<2, 64, 0, stream>>>(EWe, EW1, wbuf);

    dim3 b644(64, 4);

    // ---- layer 0 ----
    k_agg_seq<<<(N + 3) / 4, b644, 0, stream>>>(xb0, pea, row_start, srcs, Sx, Se, N);
    k_node<<<2048, b644, 0, stream>>>(x0, Sx, Se, inv_deg, Wr, Wn, We, b, x1, xb1, N, 1);
    k_st<<<2048, b644, 0, stream>>>(x1, EWs, Ebs, EWt, Ebt, Ebe, sfb, tfb, N);
    k_edge_mfma<0><<<2048, 256, 0, stream>>>(pea, srcs, pdst, eids, sfb, tfb,
                                             wbuf, Eb1, pea, nullptr, E);

    // ---- layer 1 ----
    k_agg_seq<<<(N + 3) / 4, b644, 0, stream>>>(xb1, pea, row_start, srcs, Sx, Se, N);
    k_node<<<2048, b644, 0, stream>>>(x1, Sx, Se, inv_deg,
                                      Wr + D * D, Wn + D * D, We + D * D, b + D, x2, xb0, N, 1);
    k_st<<<2048, b644, 0, stream>>>(x2, EWs + D * D, Ebs + D, EWt + D * D, Ebt + D, Ebe + D,
                                    sfb, tfb, N);
    k_edge_mfma<1><<<2048, 256, 0, stream>>>(pea, srcs, pdst, eids, sfb, tfb,
                                             wbuf + 1536, Eb1 + D, pea, outea, E);

    // ---- layer 2 ----
    k_agg_seq<<<(N + 3) / 4, b644, 0, stream>>>(xb0, pea, row_start, srcs, Sx, Se, N);
    k_node<<<2048, b644, 0, stream>>>(x2, Sx, Se, inv_deg,
                                      Wr + 2 * D * D, Wn + 2 * D * D, We + 2 * D * D, b + 2 * D,
                                      outx, nullptr, N, 0);
}

// Round 11
// 881.543 us; speedup vs baseline: 1.1183x; 1.1183x over previous
//
#include <hip/hip_runtime.h>

#define D 64
#define LAYERS 3

typedef float  f4  __attribute__((ext_vector_type(4)));
typedef short  s8v __attribute__((ext_vector_type(8)));
typedef short  s4v __attribute__((ext_vector_type(4)));
typedef unsigned short ushort_t;

__device__ __forceinline__ unsigned short f2bf(float x) {
    unsigned int u = __float_as_uint(x);
    unsigned int r = (u + 0x7fffu + ((u >> 16) & 1u)) >> 16;
    return (unsigned short)r;
}
__device__ __forceinline__ float bf2f(unsigned short h) {
    return __uint_as_float(((unsigned int)h) << 16);
}

// ---------------- CSR build ----------------

__global__ void k_count(const int* __restrict__ dst, int* __restrict__ cnt, int E) {
    int e = blockIdx.x * blockDim.x + threadIdx.x;
    if (e < E) atomicAdd(&cnt[dst[e]], 1);
}

__global__ __launch_bounds__(1024) void k_scan(const int* __restrict__ cnt,
                                               int* __restrict__ row_start,
                                               float* __restrict__ inv_deg, int N) {
    __shared__ int buf[1024];
    int tid = threadIdx.x;
    int per = (N + 1023) >> 10;
    int begin = tid * per;
    int end = min(begin + per, N);
    int s = 0;
    for (int i = begin; i < end; i++) s += cnt[i];
    buf[tid] = s;
    __syncthreads();
    for (int off = 1; off < 1024; off <<= 1) {
        int v = 0;
        if (tid >= off) v = buf[tid - off];
        __syncthreads();
        buf[tid] += v;
        __syncthreads();
    }
    int run = buf[tid] - s;
    for (int i = begin; i < end; i++) {
        row_start[i] = run;
        int c = cnt[i];
        inv_deg[i] = 1.0f / (float)(c > 1 ? c : 1);
        run += c;
    }
    if (begin < N && end == N) row_start[N] = run;
}

__global__ void k_fill(const int* __restrict__ src, const int* __restrict__ dst,
                       const int* __restrict__ row_start, int* __restrict__ cursor,
                       int* __restrict__ eids, int* __restrict__ srcs,
                       int* __restrict__ pdst, int* __restrict__ pos, int E) {
    int e = blockIdx.x * blockDim.x + threadIdx.x;
    if (e >= E) return;
    int d = dst[e];
    int p = row_start[d] + atomicAdd(&cursor[d], 1);
    eids[p] = e;
    srcs[p] = src[e];
    pdst[p] = d;
    pos[e] = p;
}

// ---------------- fused: permute ea0 -> pea (bf16, p-order) AND x0 -> xb (bf16) ----------------
__global__ __launch_bounds__(256) void k_permcvt(const float* __restrict__ ea,
                                                 const int* __restrict__ pos,
                                                 ushort_t* __restrict__ pea, int E,
                                                 const float* __restrict__ x,
                                                 ushort_t* __restrict__ xb, int xtotal8,
                                                 int pblocks) {
    if ((int)blockIdx.x < pblocks) {
        int t = blockIdx.x * blockDim.x + threadIdx.x;
        int e = t >> 3;
        if (e >= E) return;
        int seg = t & 7;
        const float* rp = ea + (size_t)e * D + seg * 8;
        f4 a0 = *(const f4*)rp;
        f4 a1 = *(const f4*)(rp + 4);
        s8v o;
        #pragma unroll
        for (int i = 0; i < 4; i++) {
            o[i]     = (short)f2bf(a0[i]);
            o[4 + i] = (short)f2bf(a1[i]);
        }
        int p = pos[e];
        *(s8v*)(pea + (size_t)p * D + seg * 8) = o;
    } else {
        int t = (blockIdx.x - pblocks) * blockDim.x + threadIdx.x;
        if (t >= xtotal8) return;
        const float* rp = x + (size_t)t * 8;
        f4 a0 = *(const f4*)rp;
        f4 a1 = *(const f4*)(rp + 4);
        s8v o;
        #pragma unroll
        for (int i = 0; i < 4; i++) {
            o[i]     = (short)f2bf(a0[i]);
            o[4 + i] = (short)f2bf(a1[i]);
        }
        *(s8v*)(xb + (size_t)t * 8) = o;
    }
}

// ---------------- prepack edge-MLP weight fragments (per-lane layout) ----------------
__global__ __launch_bounds__(64) void k_prepw(const float* __restrict__ EWe,
                                              const float* __restrict__ EW1,
                                              s8v* __restrict__ wbuf) {
    int L = blockIdx.x;
    const float* We = EWe + (size_t)L * D * D;
    const float* W1 = EW1 + (size_t)L * D * D;
    s8v* wb = wbuf + (size_t)L * 1536;
    int lane = threadIdx.x;
    int c = lane & 15, g = lane >> 4;
    #pragma unroll
    for (int nt = 0; nt < 4; nt++) {
        #pragma unroll
        for (int kt = 0; kt < 2; kt++) {
            s8v h, l, w1;
            #pragma unroll
            for (int i = 0; i < 8; i++) {
                int k1 = 32 * kt + 8 * g + i;                       // natural k (GEMM1)
                float w = We[k1 * D + 16 * nt + c];
                unsigned short hb = f2bf(w);
                h[i] = (short)hb;
                l[i] = (short)f2bf(w - bf2f(hb));
                int k2 = 32 * kt + 16 * (i >> 2) + 4 * g + (i & 3); // pi-order (GEMM2)
                w1[i] = (short)f2bf(W1[k2 * D + 16 * nt + c]);
            }
            int f = nt * 2 + kt;
            wb[(0 * 8 + f) * 64 + lane] = h;
            wb[(1 * 8 + f) * 64 + lane] = l;
            wb[(2 * 8 + f) * 64 + lane] = w1;
        }
    }
}

// ---------------- aggregation: xb gathered (bf16), pea streamed (bf16) ----------------
__global__ __launch_bounds__(256) void k_agg_seq(const ushort_t* __restrict__ xb,
                                                 const ushort_t* __restrict__ pea,
                                                 const int* __restrict__ row_start,
                                                 const int* __restrict__ srcs,
                                                 float* __restrict__ Sx, float* __restrict__ Se,
                                                 int N) {
    int n = blockIdx.x * 4 + threadIdx.y;
    if (n >= N) return;
    int j = threadIdx.x;
    int p0 = row_start[n], p1 = row_start[n + 1];
    float ax0 = 0.f, ax1 = 0.f, ax2 = 0.f, ax3 = 0.f;
    float ae0 = 0.f, ae1 = 0.f, ae2 = 0.f, ae3 = 0.f;
    int p = p0;
    for (; p + 4 <= p1; p += 4) {
        int s0 = srcs[p], s1 = srcs[p + 1], s2 = srcs[p + 2], s3 = srcs[p + 3];
        ax0 += bf2f(xb[(size_t)s0 * D + j]);
        ax1 += bf2f(xb[(size_t)s1 * D + j]);
        ax2 += bf2f(xb[(size_t)s2 * D + j]);
        ax3 += bf2f(xb[(size_t)s3 * D + j]);
        ae0 += bf2f(pea[(size_t)p * D + j]);
        ae1 += bf2f(pea[(size_t)(p + 1) * D + j]);
        ae2 += bf2f(pea[(size_t)(p + 2) * D + j]);
        ae3 += bf2f(pea[(size_t)(p + 3) * D + j]);
    }
    for (; p < p1; p++) {
        ax0 += bf2f(xb[(size_t)srcs[p] * D + j]);
        ae0 += bf2f(pea[(size_t)p * D + j]);
    }
    Sx[(size_t)n * D + j] = (ax0 + ax1) + (ax2 + ax3);
    Se[(size_t)n * D + j] = (ae0 + ae1) + (ae2 + ae3);
}

// ---------------- node update (emits f32 + bf16 copies) ----------------
__global__ __launch_bounds__(256) void k_node(const float* __restrict__ x,
                                              const float* __restrict__ Sx,
                                              const float* __restrict__ Se,
                                              const float* __restrict__ inv_deg,
                                              const float* __restrict__ Wr,
                                              const float* __restrict__ Wn,
                                              const float* __restrict__ We,
                                              const float* __restrict__ bias,
                                              float* __restrict__ xo,
                                              ushort_t* __restrict__ xob,
                                              int N, int do_relu) {
    __shared__ float sWr[D * D], sWn[D * D], sWe[D * D];
    __shared__ float rx[4][D], rsx[4][D], rse[4][D];
    int tid = threadIdx.y * 64 + threadIdx.x;
    for (int i = tid; i < D * D; i += 256) {
        sWr[i] = Wr[i];
        sWn[i] = Wn[i];
        sWe[i] = We[i];
    }
    int j = threadIdx.x;
    int ty = threadIdx.y;
    float bj = bias[j];
    for (int g = blockIdx.x; g * 4 < N; g += gridDim.x) {
        int n = g * 4 + ty;
        __syncthreads();
        if (n < N) {
            rx[ty][j]  = x[(size_t)n * D + j];
            rsx[ty][j] = Sx[(size_t)n * D + j];
            rse[ty][j] = Se[(size_t)n * D + j];
        }
        __syncthreads();
        if (n < N) {
            float a0 = 0.f, a1 = 0.f, a2 = 0.f;
            #pragma unroll 8
            for (int k = 0; k < D; k++) {
                a0 += rx[ty][k]  * sWr[k * D + j];
                a1 += rsx[ty][k] * sWn[k * D + j];
                a2 += rse[ty][k] * sWe[k * D + j];
            }
            float v = a0 + inv_deg[n] * (a1 + a2) + bj;
            if (do_relu) v = fmaxf(v, 0.f);
            xo[(size_t)n * D + j] = v;
            if (xob) xob[(size_t)n * D + j] = f2bf(v);
        }
    }
}

// ---------------- s/t features -> bf16 (be folded into sf bias) ----------------
__global__ __launch_bounds__(256) void k_st(const float* __restrict__ x,
                                            const float* __restrict__ Ws, const float* __restrict__ bs,
                                            const float* __restrict__ Wt, const float* __restrict__ bt,
                                            const float* __restrict__ be,
                                            ushort_t* __restrict__ sfb, ushort_t* __restrict__ tfb,
                                            int N) {
    __shared__ float sWs[D * D], sWt[D * D];
    __shared__ float rx[4][D];
    int tid = threadIdx.y * 64 + threadIdx.x;
    for (int i = tid; i < D * D; i += 256) {
        sWs[i] = Ws[i];
        sWt[i] = Wt[i];
    }
    int j = threadIdx.x;
    int ty = threadIdx.y;
    float bsj = bs[j] + be[j];
    float btj = bt[j];
    for (int g = blockIdx.x; g * 4 < N; g += gridDim.x) {
        int n = g * 4 + ty;
        __syncthreads();
        if (n < N) rx[ty][j] = x[(size_t)n * D + j];
        __syncthreads();
        if (n < N) {
            float a0 = 0.f, a1 = 0.f;
            #pragma unroll 8
            for (int k = 0; k < D; k++) {
                float xv = rx[ty][k];
                a0 += xv * sWs[k * D + j];
                a1 += xv * sWt[k * D + j];
            }
            sfb[(size_t)n * D + j] = f2bf(a0 + bsj);
            tfb[(size_t)n * D + j] = f2bf(a1 + btj);
        }
    }
}

// ---------------- edge MLP via MFMA (prepacked weight frags, 2 waves/EU) ----------------
// h^T = We^T @ ea^T ; out^T = W1^T @ h^T (lane's D-col = edge).
// OCCUPANCY NOTE (measured R4/R9/R10): sf[src] gather is L2-locality-bound;
// 2 waves/EU (28% occ) is the empirical optimum — 4 waves/EU thrashes L2
// (FETCH 102->279 MB, dur 143->197 us). Do not raise.
template<int MODE>
__global__ __launch_bounds__(256, 2) void k_edge_mfma(
        const ushort_t* ea_in,
        const int* __restrict__ srcA, const int* __restrict__ dstA,
        const int* __restrict__ emap,
        const ushort_t* __restrict__ sfb, const ushort_t* __restrict__ tfb,
        const s8v* __restrict__ wb,
        const float* __restrict__ b1,
        ushort_t* out_p, float* __restrict__ out_e, int E) {
    int lane = threadIdx.x & 63;
    int wid  = threadIdx.x >> 6;
    int c = lane & 15;
    int g = lane >> 4;

    s8v weh[4][2], wel[4][2], w1f[4][2];
    #pragma unroll
    for (int nt = 0; nt < 4; nt++) {
        #pragma unroll
        for (int kt = 0; kt < 2; kt++) {
            int f = nt * 2 + kt;
            weh[nt][kt] = wb[(0 * 8 + f) * 64 + lane];
            wel[nt][kt] = wb[(1 * 8 + f) * 64 + lane];
            w1f[nt][kt] = wb[(2 * 8 + f) * 64 + lane];
        }
    }
    f4 b1v[4];
    #pragma unroll
    for (int nt = 0; nt < 4; nt++) {
        b1v[nt] = *(const f4*)&b1[16 * nt + 4 * g];
    }

    int tiles = (E + 15) >> 4;
    for (int t = blockIdx.x * 4 + wid; t < tiles; t += gridDim.x * 4) {
        int idx = t * 16 + c;
        int ic = idx < E ? idx : E - 1;
        const ushort_t* ear = ea_in + (size_t)ic * D;

        s8v eaf[2];
        #pragma unroll
        for (int kt = 0; kt < 2; kt++) {
            eaf[kt] = *(const s8v*)(ear + 32 * kt + 8 * g);
        }

        // GEMM1: h^T = We^T ea^T (hi + lo)
        f4 acc[4];
        #pragma unroll
        for (int nt = 0; nt < 4; nt++) acc[nt] = (f4){0.f, 0.f, 0.f, 0.f};
        #pragma unroll
        for (int nt = 0; nt < 4; nt++) {
            #pragma unroll
            for (int kt = 0; kt < 2; kt++) {
                acc[nt] = __builtin_amdgcn_mfma_f32_16x16x32_bf16(weh[nt][kt], eaf[kt], acc[nt], 0, 0, 0);
                acc[nt] = __builtin_amdgcn_mfma_f32_16x16x32_bf16(wel[nt][kt], eaf[kt], acc[nt], 0, 0, 0);
            }
        }

        // epilogue 1: + sf[src](+be) + tf[dst], relu, pack GEMM2 B-frags
        int s = srcA[ic], d = dstA[ic];
        const ushort_t* sr = sfb + (size_t)s * D;
        const ushort_t* tr = tfb + (size_t)d * D;
        s8v hf[2];
        #pragma unroll
        for (int nt = 0; nt < 4; nt++) {
            s4v sgv = *(const s4v*)(sr + 16 * nt + 4 * g);
            s4v tgv = *(const s4v*)(tr + 16 * nt + 4 * g);
            #pragma unroll
            for (int r = 0; r < 4; r++) {
                float hv = acc[nt][r] + bf2f((ushort_t)sgv[r]) + bf2f((ushort_t)tgv[r]);
                hv = fmaxf(hv, 0.f);
                hf[nt >> 1][((nt & 1) << 2) + r] = (short)f2bf(hv);
            }
        }

        // GEMM2: out^T = W1^T h^T
        f4 out[4];
        #pragma unroll
        for (int nt = 0; nt < 4; nt++) out[nt] = (f4){0.f, 0.f, 0.f, 0.f};
        #pragma unroll
        for (int nt = 0; nt < 4; nt++) {
            #pragma unroll
            for (int kt = 0; kt < 2; kt++) {
                out[nt] = __builtin_amdgcn_mfma_f32_16x16x32_bf16(w1f[nt][kt], hf[kt], out[nt], 0, 0, 0);
            }
        }

        if (idx < E) {
            #pragma unroll
            for (int nt = 0; nt < 4; nt++) out[nt] += b1v[nt];
            ushort_t* prow = out_p + (size_t)idx * D;
            #pragma unroll
            for (int nt = 0; nt < 4; nt++) {
                s4v ov;
                #pragma unroll
                for (int r = 0; r < 4; r++) ov[r] = (short)f2bf(out[nt][r]);
                *(s4v*)(prow + 16 * nt + 4 * g) = ov;
            }
            if (MODE == 1) {
                float* orow = out_e + (size_t)emap[ic] * D;
                #pragma unroll
                for (int nt = 0; nt < 4; nt++) *(f4*)&orow[16 * nt + 4 * g] = out[nt];
            }
        }
    }
}

extern "C" void kernel_launch(void* const* d_in, const int* in_sizes, int n_in,
                              void* d_out, int out_size, void* d_ws, size_t ws_size,
                              hipStream_t stream) {
    const float* x0  = (const float*)d_in[0];
    const int*   ei  = (const int*)d_in[1];
    const float* ea0 = (const float*)d_in[2];
    const float* Wr  = (const float*)d_in[3];
    const float* Wn  = (const float*)d_in[4];
    const float* We  = (const float*)d_in[5];
    const float* b   = (const float*)d_in[6];
    const float* EWe = (const float*)d_in[7];
    const float* Ebe = (const float*)d_in[8];
    const float* EWs = (const float*)d_in[9];
    const float* Ebs = (const float*)d_in[10];
    const float* EWt = (const float*)d_in[11];
    const float* Ebt = (const float*)d_in[12];
    const float* EW1 = (const float*)d_in[13];
    const float* Eb1 = (const float*)d_in[14];

    const int N = in_sizes[0] / D;
    const int E = in_sizes[1] / 2;
    const int* src = ei;
    const int* dst = ei + E;

    char* ws = (char*)d_ws;
    size_t off = 0;
    auto alloc = [&](size_t bytes) {
        void* p = ws + off;
        off += (bytes + 255) & ~(size_t)255;
        return p;
    };
    int*      cntcur    = (int*)alloc((size_t)2 * N * 4);
    int*      cnt       = cntcur;
    int*      cursor    = cntcur + N;
    int*      row_start = (int*)alloc((size_t)(N + 1) * 4);
    int*      eids      = (int*)alloc((size_t)E * 4);
    int*      srcs      = (int*)alloc((size_t)E * 4);
    int*      pdst      = (int*)alloc((size_t)E * 4);
    int*      pos       = (int*)alloc((size_t)E * 4);
    float*    inv_deg   = (float*)alloc((size_t)N * 4);
    float*    Sx        = (float*)alloc((size_t)N * D * 4);
    float*    Se        = (float*)alloc((size_t)N * D * 4);
    float*    x1        = (float*)alloc((size_t)N * D * 4);
    float*    x2        = (float*)alloc((size_t)N * D * 4);
    ushort_t* xb0       = (ushort_t*)alloc((size_t)N * D * 2);
    ushort_t* xb1       = (ushort_t*)alloc((size_t)N * D * 2);
    ushort_t* sfb       = (ushort_t*)alloc((size_t)N * D * 2);
    ushort_t* tfb       = (ushort_t*)alloc((size_t)N * D * 2);
    s8v*      wbuf      = (s8v*)alloc((size_t)2 * 1536 * 16);
    ushort_t* pea       = (ushort_t*)alloc((size_t)E * D * 2);

    float* outx  = (float*)d_out;
    float* outea = (float*)d_out + (size_t)N * D;

    hipMemsetAsync(cntcur, 0, (size_t)2 * N * 4, stream);
    k_count<<<(E + 255) / 256, 256, 0, stream>>>(dst, cnt, E);
    k_scan<<<1, 1024, 0, stream>>>(cnt, row_start, inv_deg, N);
    k_fill<<<(E + 255) / 256, 256, 0, stream>>>(src, dst, row_start, cursor, eids, srcs, pdst, pos, E);
    {
        int pblocks = (E * 8 + 255) / 256;
        int xblocks = (N * D / 8 + 255) / 256;
        k_permcvt<<<pblocks + xblocks, 256, 0, stream>>>(ea0, pos, pea, E, x0, xb0, N * D / 8, pblocks);
    }
    k_prepw<<<2, 64, 0, stream>>>(EWe, EW1, wbuf);

    dim3 b644(64, 4);

    // ---- layer 0 ----
    k_agg_seq<<<(N + 3) / 4, b644, 0, stream>>>(xb0, pea, row_start, srcs, Sx, Se, N);
    k_node<<<2048, b644, 0, stream>>>(x0, Sx, Se, inv_deg, Wr, Wn, We, b, x1, xb1, N, 1);
    k_st<<<2048, b644, 0, stream>>>(x1, EWs, Ebs, EWt, Ebt, Ebe, sfb, tfb, N);
    k_edge_mfma<0><<<2048, 256, 0, stream>>>(pea, srcs, pdst, eids, sfb, tfb,
                                             wbuf, Eb1, pea, nullptr, E);

    // ---- layer 1 ----
    k_agg_seq<<<(N + 3) / 4, b644, 0, stream>>>(xb1, pea, row_start, srcs, Sx, Se, N);
    k_node<<<2048, b644, 0, stream>>>(x1, Sx, Se, inv_deg,
                                      Wr + D * D, Wn + D * D, We + D * D, b + D, x2, xb0, N, 1);
    k_st<<<2048, b644, 0, stream>>>(x2, EWs + D * D, Ebs + D, EWt + D * D, Ebt + D, Ebe + D,
                                    sfb, tfb, N);
    k_edge_mfma<1><<<2048, 256, 0, stream>>>(pea, srcs, pdst, eids, sfb, tfb,
                                             wbuf + 1536, Eb1 + D, pea, outea, E);

    // ---- layer 2 ----
    k_agg_seq<<<(N + 3) / 4, b644, 0, stream>>>(xb0, pea, row_start, srcs, Sx, Se, N);
    k_node<<<2048, b644, 0, stream>>>(x2, Sx, Se, inv_deg,
                                      Wr + 2 * D * D, Wn + 2 * D * D, We + 2 * D * D, b + 2 * D,
                                      outx, nullptr, N, 0);
}